// Round 3
// baseline (382.711 us; speedup 1.0000x reference)
//
#include <hip/hip_runtime.h>
#include <math.h>

#define NND 50000
#define NE  1200000
#define NG  256
#define H   64
#define H2  128
#define H4  256
#define H8  512
#define FIN 5
#define EPS_BN 1e-5f
#define EPS_MSG 1e-7f
#define NB 196          // ceil(NND/256)
#define TILES 196       // ceil(NND/256) dst tiles
#define TCAP 7168       // per-tile edge buffer cap
#define EPB 4096        // edges per bin1 block
#define NB1 293         // ceil(NE/EPB)
#define MRG (NB + 14)   // bin1 block offset inside merged k_setup
#define ELLC 72         // ELL stride (max degree bound)
#define PC 8            // pool chunks per graph
#define MT 64           // nodes per mlp block

typedef _Float16 half8 __attribute__((ext_vector_type(8)));
typedef _Float16 half4 __attribute__((ext_vector_type(4)));
typedef float floatx4 __attribute__((ext_vector_type(4)));

// ---------------- setup + bin1 merged (tilecur pre-zeroed by memset) ----------------

__global__ void __launch_bounds__(256)
k_setup(const int* __restrict__ batch, int* tilecur, int* __restrict__ gstart,
        const float* __restrict__ x, float* __restrict__ xp,
        const float* __restrict__ W1, const float* __restrict__ W2,
        _Float16* __restrict__ w1f, _Float16* __restrict__ w2f,
        const int* __restrict__ ei, unsigned* __restrict__ tilebuf) {
    __shared__ int cnt[TILES];
    __shared__ int base[TILES];
    int b = blockIdx.x, t = threadIdx.x;
    if (b >= MRG) {
        // ---- bin1 part: two-level binning pass 1 (locality-staged scatter) ----
        int bb = b - MRG;
        for (int i = t; i < TILES; i += 256) cnt[i] = 0;
        __syncthreads();
        int e0 = bb * EPB;
#pragma unroll
        for (int r = 0; r < EPB / 256; r++) {
            int e = e0 + r * 256 + t;
            if (e < NE) atomicAdd(&cnt[ei[NE + e] >> 8], 1);
        }
        __syncthreads();
        for (int i = t; i < TILES; i += 256) {
            base[i] = atomicAdd(&tilecur[i], cnt[i]);
            cnt[i] = 0;
        }
        __syncthreads();
#pragma unroll
        for (int r = 0; r < EPB / 256; r++) {
            int e = e0 + r * 256 + t;
            if (e < NE) {
                int s = ei[e], d = ei[NE + e];
                int tile = d >> 8;
                int pos = base[tile] + atomicAdd(&cnt[tile], 1);
                if (pos < TCAP)
                    __builtin_nontemporal_store(((unsigned)s << 8) | (unsigned)(d & 255),
                                                &tilebuf[(size_t)tile * TCAP + pos]);
            }
        }
        return;
    }
    if (b < NB) {
        int n = b * 256 + t;
        if (n < NND) {
            float a0 = x[n * FIN + 0], a1 = x[n * FIN + 1], a2 = x[n * FIN + 2];
            float a3 = x[n * FIN + 3], a4 = x[n * FIN + 4];
            *(float4*)&xp[n * 8] = make_float4(a0, a1, a2, a3);
            *(float4*)&xp[n * 8 + 4] = make_float4(a4, 0.f, 0.f, 0.f);
        }
        return;
    }
    if (b == NB || b == NB + 1) {
        int g = (b - NB) * 256 + t;
        if (g > NG) return;
        int lo = 0, hi = NND;
        while (lo < hi) { int mid = (lo + hi) >> 1; if (batch[mid] < g) lo = mid + 1; else hi = mid; }
        gstart[g] = lo;
        return;
    }
    int tt = (b - NB - 2) * 256 + t;
    if (tt >= 3 * 16 * 64) return;
    int lane = tt & 63, fr = (tt >> 6) & 15, l = tt >> 10;
    {
        int jt = fr >> 1, kf = fr & 1;
        int j = jt * 16 + (lane & 15);
        int k0 = kf * 32 + (lane >> 4) * 8;
#pragma unroll
        for (int i = 0; i < 8; i++)
            w1f[(((size_t)l * 16 + jt * 2 + kf) * 64 + lane) * 8 + i] =
                (_Float16)W1[(size_t)l * H * H2 + (k0 + i) * H2 + j];
    }
    {
        int ct = fr >> 2, k2f = fr & 3;
        int c = ct * 16 + (lane & 15);
        int k0 = k2f * 32 + (lane >> 4) * 8;
#pragma unroll
        for (int i = 0; i < 8; i++)
            w2f[(((size_t)l * 16 + ct * 4 + k2f) * 64 + lane) * 8 + i] =
                (_Float16)W2[(size_t)l * H2 * H + (k0 + i) * H + c];
    }
}

// ---------------- bin2: ELL assembly in LDS; dinv packed into xp[.*8+5] ----------------

__global__ void __launch_bounds__(256)
k_bin2(const int* __restrict__ tilecur, const unsigned* __restrict__ tilebuf,
       unsigned short* __restrict__ ell, int* __restrict__ deg, float* __restrict__ xp) {
    __shared__ unsigned short ell_l[256 * ELLC];  // 36 KB
    __shared__ int cnt[256];
    int tile = blockIdx.x, t = threadIdx.x;
    cnt[t] = 0;
    __syncthreads();
    int n = min(tilecur[tile], TCAP);
    for (int i = t; i < n; i += 256) {
        unsigned v = __builtin_nontemporal_load(&tilebuf[(size_t)tile * TCAP + i]);
        int dl = v & 255u;
        int slot = atomicAdd(&cnt[dl], 1);
        if (slot < ELLC) ell_l[dl * ELLC + slot] = (unsigned short)(v >> 8);
    }
    __syncthreads();
    const unsigned* s32 = (const unsigned*)ell_l;
    unsigned* d32 = (unsigned*)(ell + (size_t)tile * 256 * ELLC);
    for (int i = t; i < 256 * ELLC / 2; i += 256)
        __builtin_nontemporal_store(s32[i], &d32[i]);
    int d = tile * 256 + t;
    if (d < NND) {
        deg[d] = min(cnt[t], ELLC);
        xp[(size_t)d * 8 + 5] = rsqrtf((float)cnt[t] + 1.0f);   // packed dinv
    }
}

// ---------------- GCNConv: factored K=5, 4 nodes/wave, packed xp row (1 line/edge) ----------------

__global__ void k_gcn(const int* __restrict__ deg, const unsigned short* __restrict__ ell,
                      const float* __restrict__ xp,
                      const float* __restrict__ W,
                      const float* __restrict__ cb, const float* __restrict__ bg,
                      const float* __restrict__ bb,
                      const float* __restrict__ lg, const float* __restrict__ lb,
                      const float* __restrict__ pa,
                      _Float16* __restrict__ xcH, _Float16* __restrict__ u_h) {
    int tid = blockIdx.x * blockDim.x + threadIdx.x;
    int d = tid >> 4;
    int r = threadIdx.x & 15;
    if (d >= NND) return;
    int dg = deg[d];
    size_t base = (size_t)d * ELLC;
    float xw0 = 0.f, xw1 = 0.f, xw2 = 0.f, xw3 = 0.f, xw4 = 0.f;
    for (int i = r; i < dg; i += 16) {
        int s = (int)__builtin_nontemporal_load(&ell[base + i]);
        float4 a = *(const float4*)&xp[s * 8];
        float2 a45 = *(const float2*)&xp[s * 8 + 4];   // {x4, dinv} same 32B row
        float dv = a45.y;
        xw0 += a.x * dv; xw1 += a.y * dv; xw2 += a.z * dv;
        xw3 += a.w * dv; xw4 += a45.x * dv;
    }
#pragma unroll
    for (int off = 1; off <= 8; off <<= 1) {
        xw0 += __shfl_xor(xw0, off, 64);
        xw1 += __shfl_xor(xw1, off, 64);
        xw2 += __shfl_xor(xw2, off, 64);
        xw3 += __shfl_xor(xw3, off, 64);
        xw4 += __shfl_xor(xw4, off, 64);
    }
    float4 xa = *(const float4*)&xp[d * 8];
    float2 xa45 = *(const float2*)&xp[d * 8 + 4];
    float dd = xa45.y;
    xw0 += dd * xa.x; xw1 += dd * xa.y; xw2 += dd * xa.z;
    xw3 += dd * xa.w; xw4 += dd * xa45.x;
    float bns = rsqrtf(1.f + EPS_BN);
    float x0[4];
    float sum = 0.f, sq = 0.f;
#pragma unroll
    for (int j = 0; j < 4; j++) {
        int c = 4 * r + j;
        float s_ = xw0 * W[c] + xw1 * W[H + c] + xw2 * W[2 * H + c]
                 + xw3 * W[3 * H + c] + xw4 * W[4 * H + c];
        float v = s_ * dd + cb[c];
        v = v * (bg[c] * bns) + bb[c];
        v = fmaxf(v, 0.f);
        x0[j] = v;
        sum += v; sq += v * v;
    }
    {
        half4 xh = {(_Float16)x0[0], (_Float16)x0[1], (_Float16)x0[2], (_Float16)x0[3]};
        __builtin_nontemporal_store(xh, (half4*)&xcH[(size_t)d * H4 + 4 * r]);
    }
#pragma unroll
    for (int off = 1; off <= 8; off <<= 1) {
        sum += __shfl_xor(sum, off, 64);
        sq  += __shfl_xor(sq,  off, 64);
    }
    float mu  = sum * (1.f / H);
    float var = sq * (1.f / H) - mu * mu;
    float rs = rsqrtf(var + EPS_BN);
    half4 yh;
#pragma unroll
    for (int j = 0; j < 4; j++) {
        int c = 4 * r + j;
        float y = (x0[j] - mu) * rs * lg[c] + lb[c];
        y = (y >= 0.f) ? y : pa[c] * y;
        yh[j] = (_Float16)y;
    }
    *(half4*)&u_h[(size_t)d * H + 4 * r] = yh;   // normal store: next k_gen's gather target
}

// ---------------- GENConv softmax agg (round-0 proven; NT on ELL stream) ----------------

__global__ void k_gen(const int* __restrict__ deg, const unsigned short* __restrict__ ell,
                      const _Float16* __restrict__ u_h,
                      const float* __restrict__ tptr, int li, _Float16* __restrict__ ua_h) {
    int d = (blockIdx.x * blockDim.x + threadIdx.x) >> 6;
    int lane = threadIdx.x & 63;
    if (d >= NND) return;
    int q = lane & 15, eg = lane >> 4;
    float t = tptr[li];
    int dg = deg[d];
    size_t base = (size_t)d * ELLC;
    half4 us = *(const half4*)&u_h[(size_t)d * H + 4 * q];   // hoisted self-row read
    float4 s4 = {0.f, 0.f, 0.f, 0.f}, n4 = {0.f, 0.f, 0.f, 0.f};
    for (int i0 = 0; i0 < dg; i0 += 64) {
        int idx = i0 + lane;
        int csrv = (idx < dg) ? (int)__builtin_nontemporal_load(&ell[base + idx]) : 0;
        int chunk = min(64, dg - i0);
        for (int j = 0; j < chunk; j += 32) {
            half4 uv[8]; bool ok[8];
#pragma unroll
            for (int b2 = 0; b2 < 8; b2++) {
                int e_rel = j + 4 * b2 + eg;
                int s = __shfl(csrv, e_rel, 64);
                ok[b2] = (e_rel < chunk);
                uv[b2] = (half4){0, 0, 0, 0};
                if (ok[b2]) uv[b2] = *(const half4*)&u_h[(size_t)s * H + 4 * q];
            }
#pragma unroll
            for (int b2 = 0; b2 < 8; b2++) {
                if (ok[b2]) {
                    float m0 = fmaxf((float)uv[b2][0], 0.f) + EPS_MSG;
                    float m1 = fmaxf((float)uv[b2][1], 0.f) + EPS_MSG;
                    float m2 = fmaxf((float)uv[b2][2], 0.f) + EPS_MSG;
                    float m3 = fmaxf((float)uv[b2][3], 0.f) + EPS_MSG;
                    float e0 = __expf(m0 * t - 8.f);
                    float e1 = __expf(m1 * t - 8.f);
                    float e2 = __expf(m2 * t - 8.f);
                    float e3 = __expf(m3 * t - 8.f);
                    s4.x += e0; s4.y += e1; s4.z += e2; s4.w += e3;
                    n4.x += m0 * e0; n4.y += m1 * e1; n4.z += m2 * e2; n4.w += m3 * e3;
                }
            }
        }
    }
#pragma unroll
    for (int off = 16; off <= 32; off <<= 1) {
        s4.x += __shfl_xor(s4.x, off, 64); s4.y += __shfl_xor(s4.y, off, 64);
        s4.z += __shfl_xor(s4.z, off, 64); s4.w += __shfl_xor(s4.w, off, 64);
        n4.x += __shfl_xor(n4.x, off, 64); n4.y += __shfl_xor(n4.y, off, 64);
        n4.z += __shfl_xor(n4.z, off, 64); n4.w += __shfl_xor(n4.w, off, 64);
    }
    if (eg == 0) {
        float o0 = (float)us[0] + ((s4.x > 0.f) ? n4.x / s4.x : 0.f);
        float o1 = (float)us[1] + ((s4.y > 0.f) ? n4.y / s4.y : 0.f);
        float o2 = (float)us[2] + ((s4.z > 0.f) ? n4.z / s4.z : 0.f);
        float o3 = (float)us[3] + ((s4.w > 0.f) ? n4.w / s4.w : 0.f);
        half4 oh = {(_Float16)o0, (_Float16)o1, (_Float16)o2, (_Float16)o3};
        *(half4*)&ua_h[(size_t)d * H + 4 * q] = oh;
    }
}

// ---------------- fused MLP via MFMA (round-0 proven; NT on xcH stream) ----------------

__global__ void __launch_bounds__(256)
k_mlp(const _Float16* __restrict__ ua_h,
      const _Float16* __restrict__ w1f, const _Float16* __restrict__ w2f,
      const float* __restrict__ b1,
      const float* __restrict__ bng, const float* __restrict__ bnb,
      const float* __restrict__ b2,
      _Float16* __restrict__ xcH, int slice,
      const float* __restrict__ lg, const float* __restrict__ lb,
      const float* __restrict__ pa, _Float16* __restrict__ u_h, int do_ln) {
    __shared__ _Float16 a2[4][4][64][8];   // 16 KB
    int t = threadIdx.x;
    int w = t >> 6, l = t & 63;
    int nb = blockIdx.x * MT;
    int c_in = l & 15, quad = l >> 4;
    bool wvalid = (nb + 16 * w) < NND;

    half8 af0 = {0,0,0,0,0,0,0,0}, af1 = af0;
    {
        int node = nb + 16 * w + c_in;
        if (node < NND) {
            af0 = *(const half8*)&ua_h[(size_t)node * H + quad * 8];
            af1 = *(const half8*)&ua_h[(size_t)node * H + 32 + quad * 8];
        }
    }

    floatx4 acc[8];
#pragma unroll
    for (int jt = 0; jt < 8; jt++) acc[jt] = (floatx4){0.f, 0.f, 0.f, 0.f};
#pragma unroll
    for (int jt = 0; jt < 8; jt++) {
        half8 bf0 = *(const half8*)&w1f[((size_t)(jt * 2 + 0) * 64 + l) * 8];
        half8 bf1 = *(const half8*)&w1f[((size_t)(jt * 2 + 1) * 64 + l) * 8];
        acc[jt] = __builtin_amdgcn_mfma_f32_16x16x32_f16(af0, bf0, acc[jt], 0, 0, 0);
        acc[jt] = __builtin_amdgcn_mfma_f32_16x16x32_f16(af1, bf1, acc[jt], 0, 0, 0);
    }

    {
        float bns = rsqrtf(1.f + EPS_BN);
#pragma unroll
        for (int jt = 0; jt < 8; jt++) {
            int j = jt * 16 + c_in;
            float b1v = b1[j], bsv = bng[j] * bns, bbv = bnb[j];
            int kf2 = jt >> 1;
            int lp = 16 * ((2 * jt + (c_in >> 3)) & 3);
            int ii = c_in & 7;
#pragma unroll
            for (int reg = 0; reg < 4; reg++) {
                float z = fmaxf((acc[jt][reg] + b1v) * bsv + bbv, 0.f);
                a2[w][kf2][quad * 4 + reg + lp][ii] = (_Float16)z;
            }
        }
    }

    floatx4 acc2[4];
#pragma unroll
    for (int ct = 0; ct < 4; ct++) acc2[ct] = (floatx4){0.f, 0.f, 0.f, 0.f};
    half8 a2f[4];
#pragma unroll
    for (int k2f = 0; k2f < 4; k2f++) a2f[k2f] = *(half8*)&a2[w][k2f][l][0];
#pragma unroll
    for (int ct = 0; ct < 4; ct++) {
#pragma unroll
        for (int k2f = 0; k2f < 4; k2f++) {
            half8 bfr = *(const half8*)&w2f[((size_t)(ct * 4 + k2f) * 64 + l) * 8];
            acc2[ct] = __builtin_amdgcn_mfma_f32_16x16x32_f16(a2f[k2f], bfr, acc2[ct], 0, 0, 0);
        }
    }

    float vv[4][4];
#pragma unroll
    for (int ct = 0; ct < 4; ct++) {
        int c = ct * 16 + c_in;
        float b2v = b2[c];
#pragma unroll
        for (int reg = 0; reg < 4; reg++) {
            int node = nb + 16 * w + quad * 4 + reg;
            float v = 0.f;
            if (wvalid) {
                _Float16 prev = __builtin_nontemporal_load(&xcH[(size_t)node * H4 + slice * H + c]);
                v = (float)prev + acc2[ct][reg] + b2v;
                __builtin_nontemporal_store((_Float16)v, &xcH[(size_t)node * H4 + (slice + 1) * H + c]);
            }
            vv[ct][reg] = v;
        }
    }
    if (do_ln) {
#pragma unroll
        for (int reg = 0; reg < 4; reg++) {
            float s = (vv[0][reg] + vv[1][reg]) + (vv[2][reg] + vv[3][reg]);
            float q = (vv[0][reg] * vv[0][reg] + vv[1][reg] * vv[1][reg]) +
                      (vv[2][reg] * vv[2][reg] + vv[3][reg] * vv[3][reg]);
#pragma unroll
            for (int off = 1; off <= 8; off <<= 1) {
                s += __shfl_xor(s, off, 64);
                q += __shfl_xor(q, off, 64);
            }
            float mu = s * (1.f / H);
            float var = q * (1.f / H) - mu * mu;
            float rs = rsqrtf(var + EPS_BN);
            int node = nb + 16 * w + quad * 4 + reg;
#pragma unroll
            for (int ct = 0; ct < 4; ct++) {
                int c = ct * 16 + c_in;
                float y = (vv[ct][reg] - mu) * rs * lg[c] + lb[c];
                y = (y >= 0.f) ? y : pa[c] * y;
                if (wvalid) u_h[(size_t)node * H + c] = (_Float16)y;  // gather target: keep cached
            }
        }
    }
}

// ---------------- pooling + readout ----------------

__global__ void __launch_bounds__(256)
k_pool1(const _Float16* __restrict__ xcH, const int* __restrict__ gstart,
        float* __restrict__ psum_p, float* __restrict__ pmax_p) {
    __shared__ float4 ssum[256];
    __shared__ float4 smax[256];
    int b = blockIdx.x;
    int g = b >> 3, k = b & (PC - 1);
    int t = threadIdx.x;
    int start = gstart[g], end = gstart[g + 1];
    int len = end - start;
    int c0 = start + (len * k) / PC;
    int c1 = start + (len * (k + 1)) / PC;
    int q = t & 63, sub = t >> 6;
    float4 sum = {0.f, 0.f, 0.f, 0.f};
    float4 mx = {-INFINITY, -INFINITY, -INFINITY, -INFINITY};
    for (int n = c0 + sub; n < c1; n += 4) {
        half4 vh = __builtin_nontemporal_load((const half4*)&xcH[(size_t)n * H4 + 4 * q]);
        float v0 = (float)vh[0], v1 = (float)vh[1], v2 = (float)vh[2], v3 = (float)vh[3];
        sum.x += v0; sum.y += v1; sum.z += v2; sum.w += v3;
        mx.x = fmaxf(mx.x, v0); mx.y = fmaxf(mx.y, v1);
        mx.z = fmaxf(mx.z, v2); mx.w = fmaxf(mx.w, v3);
    }
    ssum[t] = sum; smax[t] = mx;
    __syncthreads();
    if (t < 64) {
        float4 s0 = ssum[t], s1 = ssum[t + 64], s2 = ssum[t + 128], s3 = ssum[t + 192];
        float4 m0 = smax[t], m1 = smax[t + 64], m2 = smax[t + 128], m3 = smax[t + 192];
        float4 S, M;
        S.x = (s0.x + s1.x) + (s2.x + s3.x);
        S.y = (s0.y + s1.y) + (s2.y + s3.y);
        S.z = (s0.z + s1.z) + (s2.z + s3.z);
        S.w = (s0.w + s1.w) + (s2.w + s3.w);
        M.x = fmaxf(fmaxf(m0.x, m1.x), fmaxf(m2.x, m3.x));
        M.y = fmaxf(fmaxf(m0.y, m1.y), fmaxf(m2.y, m3.y));
        M.z = fmaxf(fmaxf(m0.z, m1.z), fmaxf(m2.z, m3.z));
        M.w = fmaxf(fmaxf(m0.w, m1.w), fmaxf(m2.w, m3.w));
        *(float4*)&psum_p[(size_t)b * H4 + 4 * q] = S;
        *(float4*)&pmax_p[(size_t)b * H4 + 4 * q] = M;
    }
}

__global__ void __launch_bounds__(256)
k_readout(const float* __restrict__ psum_p, const float* __restrict__ pmax_p,
          const int* __restrict__ gstart,
          const float* __restrict__ W1, const float* __restrict__ b1,
          const float* __restrict__ W2, const float* __restrict__ b2,
          const float* __restrict__ Wo, const float* __restrict__ bo,
          float* __restrict__ out) {
    __shared__ float p0_l[H8];
    __shared__ float p1part[2][H2];
    __shared__ float p1_l[H2];
    __shared__ float p2part[4][H];
    __shared__ float p2_l[H];
    int g = blockIdx.x;
    int t = threadIdx.x;

    {
        float s = 0.f, m = -INFINITY;
#pragma unroll
        for (int k = 0; k < PC; k++) {
            s += psum_p[(size_t)(g * PC + k) * H4 + t];
            m = fmaxf(m, pmax_p[(size_t)(g * PC + k) * H4 + t]);
        }
        int cnt = gstart[g + 1] - gstart[g];
        p0_l[t] = s / fmaxf((float)cnt, 1.f);
        p0_l[H4 + t] = (cnt > 0) ? m : 0.f;
    }
    __syncthreads();

    {
        int j = t & 127, h = t >> 7;
        float acc = 0.f;
        int k0 = h * 256;
        for (int k = 0; k < 256; k++) acc += p0_l[k0 + k] * W1[(k0 + k) * H2 + j];
        p1part[h][j] = acc;
    }
    __syncthreads();
    if (t < H2) p1_l[t] = fmaxf(p1part[0][t] + p1part[1][t] + b1[t], 0.f);
    __syncthreads();

    {
        int c = t & 63, h = t >> 6;
        float acc = 0.f;
        int k0 = h * 32;
        for (int k = 0; k < 32; k++) acc += p1_l[k0 + k] * W2[(k0 + k) * H + c];
        p2part[h][c] = acc;
    }
    __syncthreads();
    if (t < H) p2_l[t] = fmaxf(((p2part[0][t] + p2part[1][t]) + (p2part[2][t] + p2part[3][t])) + b2[t], 0.f);
    __syncthreads();

    if (t < 64) {
        float v = p2_l[t] * Wo[t];
#pragma unroll
        for (int off = 32; off >= 1; off >>= 1) v += __shfl_xor(v, off, 64);
        if (t == 0) out[g] = v + bo[0];
    }
}

extern "C" void kernel_launch(void* const* d_in, const int* in_sizes, int n_in,
                              void* d_out, int out_size, void* d_ws, size_t ws_size,
                              hipStream_t stream) {
    const float* x       = (const float*)d_in[0];
    const int*   ei      = (const int*)d_in[1];
    const int*   batch   = (const int*)d_in[2];
    const float* conv1_W = (const float*)d_in[3];
    const float* conv1_b = (const float*)d_in[4];
    const float* bn1_g   = (const float*)d_in[5];
    const float* bn1_b   = (const float*)d_in[6];
    const float* ln_g    = (const float*)d_in[7];
    const float* ln_b    = (const float*)d_in[8];
    const float* prelu_a = (const float*)d_in[9];
    const float* gen_t   = (const float*)d_in[10];
    const float* mlp_W1  = (const float*)d_in[11];
    const float* mlp_b1  = (const float*)d_in[12];
    const float* mlp_bng = (const float*)d_in[13];
    const float* mlp_bnb = (const float*)d_in[14];
    const float* mlp_W2  = (const float*)d_in[15];
    const float* mlp_b2  = (const float*)d_in[16];
    const float* lin1_W  = (const float*)d_in[17];
    const float* lin1_b  = (const float*)d_in[18];
    const float* lin2_W  = (const float*)d_in[19];
    const float* lin2_b  = (const float*)d_in[20];
    const float* out_W   = (const float*)d_in[21];
    const float* out_b   = (const float*)d_in[22];
    float* out = (float*)d_out;

    float* ws   = (float*)d_ws;
    _Float16* xcH = (_Float16*)ws;             // NND*H4 halves
    float* xp   = (float*)(xcH + (size_t)NND * H4);  // NND*8 (slot 5 = dinv, written by bin2)
    int* deg    = (int*)(xp + (size_t)NND * 8);      // NND
    int* gstart = deg + NND;                   // NG+1
    int* tilecur = gstart + NG + 1;            // TILES
    unsigned* tilebuf = (unsigned*)(tilecur + TILES);      // TILES*TCAP u32
    unsigned short* ell = (unsigned short*)(tilebuf + (size_t)TILES * TCAP);  // TILES*256*ELLC u16
    uintptr_t wb = (uintptr_t)(ell + (size_t)TILES * 256 * ELLC);
    wb = (wb + 15) & ~(uintptr_t)15;
    _Float16* w1f = (_Float16*)wb;             // 3*8192 halves
    _Float16* w2f = w1f + 3 * 8192;            // 3*8192 halves
    _Float16* u_h  = w2f + 3 * 8192;           // NND*H halves
    _Float16* ua_h = u_h + (size_t)NND * H;    // NND*H halves
    uintptr_t pb = (uintptr_t)(ua_h + (size_t)NND * H);
    pb = (pb + 15) & ~(uintptr_t)15;
    float* psum_p = (float*)pb;                // NG*PC*H4
    float* pmax_p = psum_p + (size_t)NG * PC * H4;

    const int B = 256;
    const int gGCN = (NND * 16 + B - 1) / B;   // 3125
    const int gNH  = (NND * H) / B;            // 12500
    const int gMLP = (NND + MT - 1) / MT;      // 782

    // ---- tilecur zero (784 B) + merged setup/bin1 + bin2 ----
    hipMemsetAsync(tilecur, 0, TILES * sizeof(int), stream);
    k_setup<<<MRG + NB1, B, 0, stream>>>(batch, tilecur, gstart, x, xp,
                                         mlp_W1, mlp_W2, w1f, w2f, ei, tilebuf);
    k_bin2<<<TILES, B, 0, stream>>>(tilecur, tilebuf, ell, deg, xp);

    // ---- GCNConv (factored, 4 nodes/wave) + LN0/PReLU0 -> u_h ----
    k_gcn<<<gGCN, B, 0, stream>>>(deg, ell, xp, conv1_W, conv1_b, bn1_g, bn1_b,
                                  ln_g, ln_b, prelu_a, xcH, u_h);

    // ---- DeepGCN layers (all-f16 streams) ----
    for (int i = 0; i < 3; i++) {
        k_gen<<<gNH, B, 0, stream>>>(deg, ell, u_h, gen_t, i, ua_h);
        int do_ln = (i < 2) ? 1 : 0;
        k_mlp<<<gMLP, B, 0, stream>>>(ua_h,
                                      w1f + (size_t)i * 8192, w2f + (size_t)i * 8192,
                                      mlp_b1 + i * H2,
                                      mlp_bng + i * H2, mlp_bnb + i * H2,
                                      mlp_b2 + i * H,
                                      xcH, i,
                                      ln_g + (i + 1) * H, ln_b + (i + 1) * H,
                                      prelu_a + (i + 1) * H, u_h, do_ln);
    }

    // ---- pooling + readout ----
    k_pool1<<<NG * PC, B, 0, stream>>>(xcH, gstart, psum_p, pmax_p);
    k_readout<<<NG, B, 0, stream>>>(psum_p, pmax_p, gstart,
                                    lin1_W, lin1_b, lin2_W, lin2_b, out_W, out_b, out);
}

// Round 4
// 331.568 us; speedup vs baseline: 1.1542x; 1.1542x over previous
//
#include <hip/hip_runtime.h>
#include <math.h>

#define NND 50000
#define NE  1200000
#define NG  256
#define H   64
#define H2  128
#define H4  256
#define H8  512
#define FIN 5
#define EPS_BN 1e-5f
#define EPS_MSG 1e-7f
#define NB 196          // ceil(NND/256)
#define TILES 196       // ceil(NND/256) dst tiles
#define TCAP 7168       // per-tile edge buffer cap
#define EPB 4096        // edges per bin1 block
#define NB1 293         // ceil(NE/EPB)
#define MRG (NB + 14)   // bin1 block offset inside merged k_setup
#define ELLC 72         // ELL stride (max degree bound)
#define PC 8            // pool chunks per graph
#define MT 64           // nodes per mlp block

typedef _Float16 half8 __attribute__((ext_vector_type(8)));
typedef _Float16 half4 __attribute__((ext_vector_type(4)));
typedef float floatx4 __attribute__((ext_vector_type(4)));

// ---------------- setup + bin1 merged (tilecur pre-zeroed by memset) ----------------
// NOTE: tilebuf store is a PLAIN store — NT store on scattered slots caused 10x
// write amplification (round-3 counters: WRITE_SIZE 61MB for 6.5MB of data).

__global__ void __launch_bounds__(256)
k_setup(const int* __restrict__ batch, int* tilecur, int* __restrict__ gstart,
        const float* __restrict__ x, float* __restrict__ xp,
        const float* __restrict__ W1, const float* __restrict__ W2,
        _Float16* __restrict__ w1f, _Float16* __restrict__ w2f,
        const int* __restrict__ ei, unsigned* __restrict__ tilebuf) {
    __shared__ int cnt[TILES];
    __shared__ int base[TILES];
    int b = blockIdx.x, t = threadIdx.x;
    if (b >= MRG) {
        // ---- bin1 part: two-level binning pass 1 (locality-staged scatter) ----
        int bb = b - MRG;
        for (int i = t; i < TILES; i += 256) cnt[i] = 0;
        __syncthreads();
        int e0 = bb * EPB;
#pragma unroll
        for (int r = 0; r < EPB / 256; r++) {
            int e = e0 + r * 256 + t;
            if (e < NE) atomicAdd(&cnt[ei[NE + e] >> 8], 1);
        }
        __syncthreads();
        for (int i = t; i < TILES; i += 256) {
            base[i] = atomicAdd(&tilecur[i], cnt[i]);
            cnt[i] = 0;
        }
        __syncthreads();
#pragma unroll
        for (int r = 0; r < EPB / 256; r++) {
            int e = e0 + r * 256 + t;
            if (e < NE) {
                int s = ei[e], d = ei[NE + e];
                int tile = d >> 8;
                int pos = base[tile] + atomicAdd(&cnt[tile], 1);
                if (pos < TCAP)
                    tilebuf[(size_t)tile * TCAP + pos] = ((unsigned)s << 8) | (unsigned)(d & 255);
            }
        }
        return;
    }
    if (b < NB) {
        int n = b * 256 + t;
        if (n < NND) {
            float a0 = x[n * FIN + 0], a1 = x[n * FIN + 1], a2 = x[n * FIN + 2];
            float a3 = x[n * FIN + 3], a4 = x[n * FIN + 4];
            *(float4*)&xp[n * 8] = make_float4(a0, a1, a2, a3);
            *(float4*)&xp[n * 8 + 4] = make_float4(a4, 0.f, 0.f, 0.f);
        }
        return;
    }
    if (b == NB || b == NB + 1) {
        int g = (b - NB) * 256 + t;
        if (g > NG) return;
        int lo = 0, hi = NND;
        while (lo < hi) { int mid = (lo + hi) >> 1; if (batch[mid] < g) lo = mid + 1; else hi = mid; }
        gstart[g] = lo;
        return;
    }
    int tt = (b - NB - 2) * 256 + t;
    if (tt >= 3 * 16 * 64) return;
    int lane = tt & 63, fr = (tt >> 6) & 15, l = tt >> 10;
    {
        int jt = fr >> 1, kf = fr & 1;
        int j = jt * 16 + (lane & 15);
        int k0 = kf * 32 + (lane >> 4) * 8;
#pragma unroll
        for (int i = 0; i < 8; i++)
            w1f[(((size_t)l * 16 + jt * 2 + kf) * 64 + lane) * 8 + i] =
                (_Float16)W1[(size_t)l * H * H2 + (k0 + i) * H2 + j];
    }
    {
        int ct = fr >> 2, k2f = fr & 3;
        int c = ct * 16 + (lane & 15);
        int k0 = k2f * 32 + (lane >> 4) * 8;
#pragma unroll
        for (int i = 0; i < 8; i++)
            w2f[(((size_t)l * 16 + ct * 4 + k2f) * 64 + lane) * 8 + i] =
                (_Float16)W2[(size_t)l * H2 * H + (k0 + i) * H + c];
    }
}

// ---------------- bin2: ELL assembly in LDS; dinv packed into xp[.*8+5] ----------------

__global__ void __launch_bounds__(256)
k_bin2(const int* __restrict__ tilecur, const unsigned* __restrict__ tilebuf,
       unsigned short* __restrict__ ell, int* __restrict__ deg, float* __restrict__ xp) {
    __shared__ unsigned short ell_l[256 * ELLC];  // 36 KB
    __shared__ int cnt[256];
    int tile = blockIdx.x, t = threadIdx.x;
    cnt[t] = 0;
    __syncthreads();
    int n = min(tilecur[tile], TCAP);
    for (int i = t; i < n; i += 256) {
        unsigned v = __builtin_nontemporal_load(&tilebuf[(size_t)tile * TCAP + i]);
        int dl = v & 255u;
        int slot = atomicAdd(&cnt[dl], 1);
        if (slot < ELLC) ell_l[dl * ELLC + slot] = (unsigned short)(v >> 8);
    }
    __syncthreads();
    const unsigned* s32 = (const unsigned*)ell_l;
    unsigned* d32 = (unsigned*)(ell + (size_t)tile * 256 * ELLC);
    for (int i = t; i < 256 * ELLC / 2; i += 256) d32[i] = s32[i];
    int d = tile * 256 + t;
    if (d < NND) {
        deg[d] = min(cnt[t], ELLC);
        xp[(size_t)d * 8 + 5] = rsqrtf((float)cnt[t] + 1.0f);   // packed dinv
    }
}

// ---------------- GCNConv: factored K=5, 4 nodes/wave, packed xp row (1 line/edge) ----------------

__global__ void k_gcn(const int* __restrict__ deg, const unsigned short* __restrict__ ell,
                      const float* __restrict__ xp,
                      const float* __restrict__ W,
                      const float* __restrict__ cb, const float* __restrict__ bg,
                      const float* __restrict__ bb,
                      const float* __restrict__ lg, const float* __restrict__ lb,
                      const float* __restrict__ pa,
                      _Float16* __restrict__ xcH, _Float16* __restrict__ u_h) {
    int tid = blockIdx.x * blockDim.x + threadIdx.x;
    int d = tid >> 4;
    int r = threadIdx.x & 15;
    if (d >= NND) return;
    int dg = deg[d];
    size_t base = (size_t)d * ELLC;
    float xw0 = 0.f, xw1 = 0.f, xw2 = 0.f, xw3 = 0.f, xw4 = 0.f;
    for (int i = r; i < dg; i += 16) {
        int s = (int)__builtin_nontemporal_load(&ell[base + i]);
        float4 a = *(const float4*)&xp[s * 8];
        float2 a45 = *(const float2*)&xp[s * 8 + 4];   // {x4, dinv} same 32B row
        float dv = a45.y;
        xw0 += a.x * dv; xw1 += a.y * dv; xw2 += a.z * dv;
        xw3 += a.w * dv; xw4 += a45.x * dv;
    }
#pragma unroll
    for (int off = 1; off <= 8; off <<= 1) {
        xw0 += __shfl_xor(xw0, off, 64);
        xw1 += __shfl_xor(xw1, off, 64);
        xw2 += __shfl_xor(xw2, off, 64);
        xw3 += __shfl_xor(xw3, off, 64);
        xw4 += __shfl_xor(xw4, off, 64);
    }
    float4 xa = *(const float4*)&xp[d * 8];
    float2 xa45 = *(const float2*)&xp[d * 8 + 4];
    float dd = xa45.y;
    xw0 += dd * xa.x; xw1 += dd * xa.y; xw2 += dd * xa.z;
    xw3 += dd * xa.w; xw4 += dd * xa45.x;
    float bns = rsqrtf(1.f + EPS_BN);
    float x0[4];
    float sum = 0.f, sq = 0.f;
#pragma unroll
    for (int j = 0; j < 4; j++) {
        int c = 4 * r + j;
        float s_ = xw0 * W[c] + xw1 * W[H + c] + xw2 * W[2 * H + c]
                 + xw3 * W[3 * H + c] + xw4 * W[4 * H + c];
        float v = s_ * dd + cb[c];
        v = v * (bg[c] * bns) + bb[c];
        v = fmaxf(v, 0.f);
        x0[j] = v;
        sum += v; sq += v * v;
    }
    {
        half4 xh = {(_Float16)x0[0], (_Float16)x0[1], (_Float16)x0[2], (_Float16)x0[3]};
        *(half4*)&xcH[(size_t)d * H4 + 4 * r] = xh;
    }
#pragma unroll
    for (int off = 1; off <= 8; off <<= 1) {
        sum += __shfl_xor(sum, off, 64);
        sq  += __shfl_xor(sq,  off, 64);
    }
    float mu  = sum * (1.f / H);
    float var = sq * (1.f / H) - mu * mu;
    float rs = rsqrtf(var + EPS_BN);
    half4 yh;
#pragma unroll
    for (int j = 0; j < 4; j++) {
        int c = 4 * r + j;
        float y = (x0[j] - mu) * rs * lg[c] + lb[c];
        y = (y >= 0.f) ? y : pa[c] * y;
        yh[j] = (_Float16)y;
    }
    *(half4*)&u_h[(size_t)d * H + 4 * r] = yh;
}

// ---------------- GENConv softmax agg (NT load on ELL stream only) ----------------

__global__ void k_gen(const int* __restrict__ deg, const unsigned short* __restrict__ ell,
                      const _Float16* __restrict__ u_h,
                      const float* __restrict__ tptr, int li, _Float16* __restrict__ ua_h) {
    int d = (blockIdx.x * blockDim.x + threadIdx.x) >> 6;
    int lane = threadIdx.x & 63;
    if (d >= NND) return;
    int q = lane & 15, eg = lane >> 4;
    float t = tptr[li];
    int dg = deg[d];
    size_t base = (size_t)d * ELLC;
    half4 us = *(const half4*)&u_h[(size_t)d * H + 4 * q];   // hoisted self-row read
    float4 s4 = {0.f, 0.f, 0.f, 0.f}, n4 = {0.f, 0.f, 0.f, 0.f};
    for (int i0 = 0; i0 < dg; i0 += 64) {
        int idx = i0 + lane;
        int csrv = (idx < dg) ? (int)__builtin_nontemporal_load(&ell[base + idx]) : 0;
        int chunk = min(64, dg - i0);
        for (int j = 0; j < chunk; j += 32) {
            half4 uv[8]; bool ok[8];
#pragma unroll
            for (int b2 = 0; b2 < 8; b2++) {
                int e_rel = j + 4 * b2 + eg;
                int s = __shfl(csrv, e_rel, 64);
                ok[b2] = (e_rel < chunk);
                uv[b2] = (half4){0, 0, 0, 0};
                if (ok[b2]) uv[b2] = *(const half4*)&u_h[(size_t)s * H + 4 * q];
            }
#pragma unroll
            for (int b2 = 0; b2 < 8; b2++) {
                if (ok[b2]) {
                    float m0 = fmaxf((float)uv[b2][0], 0.f) + EPS_MSG;
                    float m1 = fmaxf((float)uv[b2][1], 0.f) + EPS_MSG;
                    float m2 = fmaxf((float)uv[b2][2], 0.f) + EPS_MSG;
                    float m3 = fmaxf((float)uv[b2][3], 0.f) + EPS_MSG;
                    float e0 = __expf(m0 * t - 8.f);
                    float e1 = __expf(m1 * t - 8.f);
                    float e2 = __expf(m2 * t - 8.f);
                    float e3 = __expf(m3 * t - 8.f);
                    s4.x += e0; s4.y += e1; s4.z += e2; s4.w += e3;
                    n4.x += m0 * e0; n4.y += m1 * e1; n4.z += m2 * e2; n4.w += m3 * e3;
                }
            }
        }
    }
#pragma unroll
    for (int off = 16; off <= 32; off <<= 1) {
        s4.x += __shfl_xor(s4.x, off, 64); s4.y += __shfl_xor(s4.y, off, 64);
        s4.z += __shfl_xor(s4.z, off, 64); s4.w += __shfl_xor(s4.w, off, 64);
        n4.x += __shfl_xor(n4.x, off, 64); n4.y += __shfl_xor(n4.y, off, 64);
        n4.z += __shfl_xor(n4.z, off, 64); n4.w += __shfl_xor(n4.w, off, 64);
    }
    if (eg == 0) {
        float o0 = (float)us[0] + ((s4.x > 0.f) ? n4.x / s4.x : 0.f);
        float o1 = (float)us[1] + ((s4.y > 0.f) ? n4.y / s4.y : 0.f);
        float o2 = (float)us[2] + ((s4.z > 0.f) ? n4.z / s4.z : 0.f);
        float o3 = (float)us[3] + ((s4.w > 0.f) ? n4.w / s4.w : 0.f);
        half4 oh = {(_Float16)o0, (_Float16)o1, (_Float16)o2, (_Float16)o3};
        *(half4*)&ua_h[(size_t)d * H + 4 * q] = oh;
    }
}

// ---------------- fused MLP via MFMA (round-0 semantics: plain loads/stores) ----------------

__global__ void __launch_bounds__(256)
k_mlp(const _Float16* __restrict__ ua_h,
      const _Float16* __restrict__ w1f, const _Float16* __restrict__ w2f,
      const float* __restrict__ b1,
      const float* __restrict__ bng, const float* __restrict__ bnb,
      const float* __restrict__ b2,
      _Float16* __restrict__ xcH, int slice,
      const float* __restrict__ lg, const float* __restrict__ lb,
      const float* __restrict__ pa, _Float16* __restrict__ u_h, int do_ln) {
    __shared__ _Float16 a2[4][4][64][8];   // 16 KB
    int t = threadIdx.x;
    int w = t >> 6, l = t & 63;
    int nb = blockIdx.x * MT;
    int c_in = l & 15, quad = l >> 4;
    bool wvalid = (nb + 16 * w) < NND;

    half8 af0 = {0,0,0,0,0,0,0,0}, af1 = af0;
    {
        int node = nb + 16 * w + c_in;
        if (node < NND) {
            af0 = *(const half8*)&ua_h[(size_t)node * H + quad * 8];
            af1 = *(const half8*)&ua_h[(size_t)node * H + 32 + quad * 8];
        }
    }

    floatx4 acc[8];
#pragma unroll
    for (int jt = 0; jt < 8; jt++) acc[jt] = (floatx4){0.f, 0.f, 0.f, 0.f};
#pragma unroll
    for (int jt = 0; jt < 8; jt++) {
        half8 bf0 = *(const half8*)&w1f[((size_t)(jt * 2 + 0) * 64 + l) * 8];
        half8 bf1 = *(const half8*)&w1f[((size_t)(jt * 2 + 1) * 64 + l) * 8];
        acc[jt] = __builtin_amdgcn_mfma_f32_16x16x32_f16(af0, bf0, acc[jt], 0, 0, 0);
        acc[jt] = __builtin_amdgcn_mfma_f32_16x16x32_f16(af1, bf1, acc[jt], 0, 0, 0);
    }

    {
        float bns = rsqrtf(1.f + EPS_BN);
#pragma unroll
        for (int jt = 0; jt < 8; jt++) {
            int j = jt * 16 + c_in;
            float b1v = b1[j], bsv = bng[j] * bns, bbv = bnb[j];
            int kf2 = jt >> 1;
            int lp = 16 * ((2 * jt + (c_in >> 3)) & 3);
            int ii = c_in & 7;
#pragma unroll
            for (int reg = 0; reg < 4; reg++) {
                float z = fmaxf((acc[jt][reg] + b1v) * bsv + bbv, 0.f);
                a2[w][kf2][quad * 4 + reg + lp][ii] = (_Float16)z;
            }
        }
    }

    floatx4 acc2[4];
#pragma unroll
    for (int ct = 0; ct < 4; ct++) acc2[ct] = (floatx4){0.f, 0.f, 0.f, 0.f};
    half8 a2f[4];
#pragma unroll
    for (int k2f = 0; k2f < 4; k2f++) a2f[k2f] = *(half8*)&a2[w][k2f][l][0];
#pragma unroll
    for (int ct = 0; ct < 4; ct++) {
#pragma unroll
        for (int k2f = 0; k2f < 4; k2f++) {
            half8 bfr = *(const half8*)&w2f[((size_t)(ct * 4 + k2f) * 64 + l) * 8];
            acc2[ct] = __builtin_amdgcn_mfma_f32_16x16x32_f16(a2f[k2f], bfr, acc2[ct], 0, 0, 0);
        }
    }

    float vv[4][4];
#pragma unroll
    for (int ct = 0; ct < 4; ct++) {
        int c = ct * 16 + c_in;
        float b2v = b2[c];
#pragma unroll
        for (int reg = 0; reg < 4; reg++) {
            int node = nb + 16 * w + quad * 4 + reg;
            float v = 0.f;
            if (wvalid) {
                v = (float)xcH[(size_t)node * H4 + slice * H + c] + acc2[ct][reg] + b2v;
                xcH[(size_t)node * H4 + (slice + 1) * H + c] = (_Float16)v;
            }
            vv[ct][reg] = v;
        }
    }
    if (do_ln) {
#pragma unroll
        for (int reg = 0; reg < 4; reg++) {
            float s = (vv[0][reg] + vv[1][reg]) + (vv[2][reg] + vv[3][reg]);
            float q = (vv[0][reg] * vv[0][reg] + vv[1][reg] * vv[1][reg]) +
                      (vv[2][reg] * vv[2][reg] + vv[3][reg] * vv[3][reg]);
#pragma unroll
            for (int off = 1; off <= 8; off <<= 1) {
                s += __shfl_xor(s, off, 64);
                q += __shfl_xor(q, off, 64);
            }
            float mu = s * (1.f / H);
            float var = q * (1.f / H) - mu * mu;
            float rs = rsqrtf(var + EPS_BN);
            int node = nb + 16 * w + quad * 4 + reg;
#pragma unroll
            for (int ct = 0; ct < 4; ct++) {
                int c = ct * 16 + c_in;
                float y = (vv[ct][reg] - mu) * rs * lg[c] + lb[c];
                y = (y >= 0.f) ? y : pa[c] * y;
                if (wvalid) u_h[(size_t)node * H + c] = (_Float16)y;
            }
        }
    }
}

// ---------------- pooling + readout ----------------

__global__ void __launch_bounds__(256)
k_pool1(const _Float16* __restrict__ xcH, const int* __restrict__ gstart,
        float* __restrict__ psum_p, float* __restrict__ pmax_p) {
    __shared__ float4 ssum[256];
    __shared__ float4 smax[256];
    int b = blockIdx.x;
    int g = b >> 3, k = b & (PC - 1);
    int t = threadIdx.x;
    int start = gstart[g], end = gstart[g + 1];
    int len = end - start;
    int c0 = start + (len * k) / PC;
    int c1 = start + (len * (k + 1)) / PC;
    int q = t & 63, sub = t >> 6;
    float4 sum = {0.f, 0.f, 0.f, 0.f};
    float4 mx = {-INFINITY, -INFINITY, -INFINITY, -INFINITY};
    for (int n = c0 + sub; n < c1; n += 4) {
        half4 vh = __builtin_nontemporal_load((const half4*)&xcH[(size_t)n * H4 + 4 * q]);
        float v0 = (float)vh[0], v1 = (float)vh[1], v2 = (float)vh[2], v3 = (float)vh[3];
        sum.x += v0; sum.y += v1; sum.z += v2; sum.w += v3;
        mx.x = fmaxf(mx.x, v0); mx.y = fmaxf(mx.y, v1);
        mx.z = fmaxf(mx.z, v2); mx.w = fmaxf(mx.w, v3);
    }
    ssum[t] = sum; smax[t] = mx;
    __syncthreads();
    if (t < 64) {
        float4 s0 = ssum[t], s1 = ssum[t + 64], s2 = ssum[t + 128], s3 = ssum[t + 192];
        float4 m0 = smax[t], m1 = smax[t + 64], m2 = smax[t + 128], m3 = smax[t + 192];
        float4 S, M;
        S.x = (s0.x + s1.x) + (s2.x + s3.x);
        S.y = (s0.y + s1.y) + (s2.y + s3.y);
        S.z = (s0.z + s1.z) + (s2.z + s3.z);
        S.w = (s0.w + s1.w) + (s2.w + s3.w);
        M.x = fmaxf(fmaxf(m0.x, m1.x), fmaxf(m2.x, m3.x));
        M.y = fmaxf(fmaxf(m0.y, m1.y), fmaxf(m2.y, m3.y));
        M.z = fmaxf(fmaxf(m0.z, m1.z), fmaxf(m2.z, m3.z));
        M.w = fmaxf(fmaxf(m0.w, m1.w), fmaxf(m2.w, m3.w));
        *(float4*)&psum_p[(size_t)b * H4 + 4 * q] = S;
        *(float4*)&pmax_p[(size_t)b * H4 + 4 * q] = M;
    }
}

__global__ void __launch_bounds__(256)
k_readout(const float* __restrict__ psum_p, const float* __restrict__ pmax_p,
          const int* __restrict__ gstart,
          const float* __restrict__ W1, const float* __restrict__ b1,
          const float* __restrict__ W2, const float* __restrict__ b2,
          const float* __restrict__ Wo, const float* __restrict__ bo,
          float* __restrict__ out) {
    __shared__ float p0_l[H8];
    __shared__ float p1part[2][H2];
    __shared__ float p1_l[H2];
    __shared__ float p2part[4][H];
    __shared__ float p2_l[H];
    int g = blockIdx.x;
    int t = threadIdx.x;

    {
        float s = 0.f, m = -INFINITY;
#pragma unroll
        for (int k = 0; k < PC; k++) {
            s += psum_p[(size_t)(g * PC + k) * H4 + t];
            m = fmaxf(m, pmax_p[(size_t)(g * PC + k) * H4 + t]);
        }
        int cnt = gstart[g + 1] - gstart[g];
        p0_l[t] = s / fmaxf((float)cnt, 1.f);
        p0_l[H4 + t] = (cnt > 0) ? m : 0.f;
    }
    __syncthreads();

    {
        int j = t & 127, h = t >> 7;
        float acc = 0.f;
        int k0 = h * 256;
        for (int k = 0; k < 256; k++) acc += p0_l[k0 + k] * W1[(k0 + k) * H2 + j];
        p1part[h][j] = acc;
    }
    __syncthreads();
    if (t < H2) p1_l[t] = fmaxf(p1part[0][t] + p1part[1][t] + b1[t], 0.f);
    __syncthreads();

    {
        int c = t & 63, h = t >> 6;
        float acc = 0.f;
        int k0 = h * 32;
        for (int k = 0; k < 32; k++) acc += p1_l[k0 + k] * W2[(k0 + k) * H + c];
        p2part[h][c] = acc;
    }
    __syncthreads();
    if (t < H) p2_l[t] = fmaxf(((p2part[0][t] + p2part[1][t]) + (p2part[2][t] + p2part[3][t])) + b2[t], 0.f);
    __syncthreads();

    if (t < 64) {
        float v = p2_l[t] * Wo[t];
#pragma unroll
        for (int off = 32; off >= 1; off >>= 1) v += __shfl_xor(v, off, 64);
        if (t == 0) out[g] = v + bo[0];
    }
}

extern "C" void kernel_launch(void* const* d_in, const int* in_sizes, int n_in,
                              void* d_out, int out_size, void* d_ws, size_t ws_size,
                              hipStream_t stream) {
    const float* x       = (const float*)d_in[0];
    const int*   ei      = (const int*)d_in[1];
    const int*   batch   = (const int*)d_in[2];
    const float* conv1_W = (const float*)d_in[3];
    const float* conv1_b = (const float*)d_in[4];
    const float* bn1_g   = (const float*)d_in[5];
    const float* bn1_b   = (const float*)d_in[6];
    const float* ln_g    = (const float*)d_in[7];
    const float* ln_b    = (const float*)d_in[8];
    const float* prelu_a = (const float*)d_in[9];
    const float* gen_t   = (const float*)d_in[10];
    const float* mlp_W1  = (const float*)d_in[11];
    const float* mlp_b1  = (const float*)d_in[12];
    const float* mlp_bng = (const float*)d_in[13];
    const float* mlp_bnb = (const float*)d_in[14];
    const float* mlp_W2  = (const float*)d_in[15];
    const float* mlp_b2  = (const float*)d_in[16];
    const float* lin1_W  = (const float*)d_in[17];
    const float* lin1_b  = (const float*)d_in[18];
    const float* lin2_W  = (const float*)d_in[19];
    const float* lin2_b  = (const float*)d_in[20];
    const float* out_W   = (const float*)d_in[21];
    const float* out_b   = (const float*)d_in[22];
    float* out = (float*)d_out;

    float* ws   = (float*)d_ws;
    _Float16* xcH = (_Float16*)ws;             // NND*H4 halves
    float* xp   = (float*)(xcH + (size_t)NND * H4);  // NND*8 (slot 5 = dinv, written by bin2)
    int* deg    = (int*)(xp + (size_t)NND * 8);      // NND
    int* gstart = deg + NND;                   // NG+1
    int* tilecur = gstart + NG + 1;            // TILES
    unsigned* tilebuf = (unsigned*)(tilecur + TILES);      // TILES*TCAP u32
    unsigned short* ell = (unsigned short*)(tilebuf + (size_t)TILES * TCAP);  // TILES*256*ELLC u16
    uintptr_t wb = (uintptr_t)(ell + (size_t)TILES * 256 * ELLC);
    wb = (wb + 15) & ~(uintptr_t)15;
    _Float16* w1f = (_Float16*)wb;             // 3*8192 halves
    _Float16* w2f = w1f + 3 * 8192;            // 3*8192 halves
    _Float16* u_h  = w2f + 3 * 8192;           // NND*H halves
    _Float16* ua_h = u_h + (size_t)NND * H;    // NND*H halves
    uintptr_t pb = (uintptr_t)(ua_h + (size_t)NND * H);
    pb = (pb + 15) & ~(uintptr_t)15;
    float* psum_p = (float*)pb;                // NG*PC*H4
    float* pmax_p = psum_p + (size_t)NG * PC * H4;

    const int B = 256;
    const int gGCN = (NND * 16 + B - 1) / B;   // 3125
    const int gNH  = (NND * H) / B;            // 12500
    const int gMLP = (NND + MT - 1) / MT;      // 782

    // ---- tilecur zero (784 B) + merged setup/bin1 + bin2 ----
    hipMemsetAsync(tilecur, 0, TILES * sizeof(int), stream);
    k_setup<<<MRG + NB1, B, 0, stream>>>(batch, tilecur, gstart, x, xp,
                                         mlp_W1, mlp_W2, w1f, w2f, ei, tilebuf);
    k_bin2<<<TILES, B, 0, stream>>>(tilecur, tilebuf, ell, deg, xp);

    // ---- GCNConv (factored, 4 nodes/wave) + LN0/PReLU0 -> u_h ----
    k_gcn<<<gGCN, B, 0, stream>>>(deg, ell, xp, conv1_W, conv1_b, bn1_g, bn1_b,
                                  ln_g, ln_b, prelu_a, xcH, u_h);

    // ---- DeepGCN layers (all-f16 streams) ----
    for (int i = 0; i < 3; i++) {
        k_gen<<<gNH, B, 0, stream>>>(deg, ell, u_h, gen_t, i, ua_h);
        int do_ln = (i < 2) ? 1 : 0;
        k_mlp<<<gMLP, B, 0, stream>>>(ua_h,
                                      w1f + (size_t)i * 8192, w2f + (size_t)i * 8192,
                                      mlp_b1 + i * H2,
                                      mlp_bng + i * H2, mlp_bnb + i * H2,
                                      mlp_b2 + i * H,
                                      xcH, i,
                                      ln_g + (i + 1) * H, ln_b + (i + 1) * H,
                                      prelu_a + (i + 1) * H, u_h, do_ln);
    }

    // ---- pooling + readout ----
    k_pool1<<<NG * PC, B, 0, stream>>>(xcH, gstart, psum_p, pmax_p);
    k_readout<<<NG, B, 0, stream>>>(psum_p, pmax_p, gstart,
                                    lin1_W, lin1_b, lin2_W, lin2_b, out_W, out_b, out);
}